// Round 10
// baseline (340.663 us; speedup 1.0000x reference)
//
#include <hip/hip_runtime.h>
#include <math.h>

typedef __bf16 bf16x8 __attribute__((ext_vector_type(8)));
typedef float  f32x4  __attribute__((ext_vector_type(4)));
typedef unsigned short u16x8 __attribute__((ext_vector_type(8)));

__device__ __forceinline__ float bf2f(unsigned short u) {
    return __uint_as_float(((unsigned int)u) << 16);
}
__device__ __forceinline__ unsigned short f2bf_n(float f) {
    return __builtin_bit_cast(unsigned short, (__bf16)f);  // native cvt (RNE)
}

// dims
#define BATCH 4
#define SEQ 512
#define DM 1024
#define NH 16
#define DH 64
#define DFF 4096
#define MROWS (BATCH * SEQ)   // 2048

__global__ __launch_bounds__(256) void fill0_kernel(float* __restrict__ out) {
    out[blockIdx.x * 256 + threadIdx.x] = 0.0f;  // ws-too-small sentinel
}

// ---------------- 1) sinusoidal emb + silu ----------------
__global__ void semb_kernel(const int* __restrict__ ts, float* __restrict__ semb) {
    int b = blockIdx.x;
    float x = (float)ts[b] * 40.0f;
    for (int j = threadIdx.x; j < 1024; j += 256) {
        int idx = (j < 512) ? j : (j - 512);
        float fr = expf(-9.210340371976184f * (float)idx / 511.0f);
        float e = x * fr;
        float v = (j < 512) ? sinf(e) : cosf(e);
        semb[b * 1024 + j] = v / (1.0f + expf(-v));
    }
}

// ---------------- 2a) ada partials (verified) ----------------
__global__ __launch_bounds__(256) void ada_part_kernel(const float* __restrict__ semb,
                                                       const float* __restrict__ W,
                                                       float* __restrict__ part) {
    const int nb = blockIdx.x, kc = blockIdx.y;
    const int t = threadIdx.x;
    __shared__ float e_s[4][64];
    e_s[t >> 6][t & 63] = semb[(t >> 6) * 1024 + kc * 64 + (t & 63)];
    __syncthreads();
    const int n = nb * 128 + (t & 127);
    const int half = t >> 7;
    float a0 = 0.f, a1 = 0.f, a2 = 0.f, a3 = 0.f;
    const int kk0 = half * 32;
    #pragma unroll 8
    for (int kk = kk0; kk < kk0 + 32; ++kk) {
        const float w = W[(size_t)(kc * 64 + kk) * 2048 + n];
        a0 += e_s[0][kk] * w; a1 += e_s[1][kk] * w;
        a2 += e_s[2][kk] * w; a3 += e_s[3][kk] * w;
    }
    const int j = kc * 2 + half;
    float* p = part + (size_t)j * 4 * 2048 + n;
    p[0] = a0; p[2048] = a1; p[2 * 2048] = a2; p[3 * 2048] = a3;
}

// ---------------- 2b) ada reduce (verified) ----------------
__global__ __launch_bounds__(256) void ada_red_kernel(const float* __restrict__ part,
                                                      const float* __restrict__ bias,
                                                      float* __restrict__ ss) {
    const int idx = blockIdx.x * 256 + threadIdx.x;
    const int b = idx >> 11, n = idx & 2047;
    float acc = bias[n];
    #pragma unroll 8
    for (int j = 0; j < 32; ++j) acc += part[((size_t)j * 4 + b) * 2048 + n];
    ss[b * 2048 + n] = acc;
}

// ---------------- 3) AdaLN: f32 src -> bf16 xb ----------------
__global__ __launch_bounds__(256) void adaln_kernel(const float* __restrict__ src,
                                                    const float* __restrict__ ss,
                                                    unsigned short* __restrict__ xb) {
    int r = blockIdx.x;
    int b = r >> 9;
    int t = threadIdx.x;
    float4 v4 = *reinterpret_cast<const float4*>(&src[(size_t)r * DM + t * 4]);
    float v[4] = {v4.x, v4.y, v4.z, v4.w};
    float s = v[0] + v[1] + v[2] + v[3];
    float q = v[0]*v[0] + v[1]*v[1] + v[2]*v[2] + v[3]*v[3];
    #pragma unroll
    for (int off = 32; off > 0; off >>= 1) { s += __shfl_down(s, off); q += __shfl_down(q, off); }
    __shared__ float red[8];
    if ((t & 63) == 0) { red[t >> 6] = s; red[4 + (t >> 6)] = q; }
    __syncthreads();
    s = red[0] + red[1] + red[2] + red[3];
    q = red[4] + red[5] + red[6] + red[7];
    float mean = s * (1.0f / DM);
    float var = q * (1.0f / DM) - mean * mean;
    float rstd = rsqrtf(var + 1e-5f);
    ushort4 o;
    o.x = f2bf_n((v[0]-mean)*rstd*(1.0f+ss[b*2048 + t*4+0]) + ss[b*2048+1024 + t*4+0]);
    o.y = f2bf_n((v[1]-mean)*rstd*(1.0f+ss[b*2048 + t*4+1]) + ss[b*2048+1024 + t*4+1]);
    o.z = f2bf_n((v[2]-mean)*rstd*(1.0f+ss[b*2048 + t*4+2]) + ss[b*2048+1024 + t*4+2]);
    o.w = f2bf_n((v[3]-mean)*rstd*(1.0f+ss[b*2048 + t*4+3]) + ss[b*2048+1024 + t*4+3]);
    *reinterpret_cast<ushort4*>(&xb[(size_t)r * DM + t * 4]) = o;
}

// ---------------- LN2: bf16 -> bf16 ----------------
__global__ __launch_bounds__(256) void ln2_kernel(const unsigned short* __restrict__ x,
                                                  const float* __restrict__ g2,
                                                  const float* __restrict__ beta2,
                                                  unsigned short* __restrict__ hout) {
    int r = blockIdx.x;
    int t = threadIdx.x;
    ushort4 s4 = *reinterpret_cast<const ushort4*>(&x[(size_t)r * DM + t * 4]);
    float v[4] = {bf2f(s4.x), bf2f(s4.y), bf2f(s4.z), bf2f(s4.w)};
    float s = v[0] + v[1] + v[2] + v[3];
    float q = v[0]*v[0] + v[1]*v[1] + v[2]*v[2] + v[3]*v[3];
    #pragma unroll
    for (int off = 32; off > 0; off >>= 1) { s += __shfl_down(s, off); q += __shfl_down(q, off); }
    __shared__ float red[8];
    if ((t & 63) == 0) { red[t >> 6] = s; red[4 + (t >> 6)] = q; }
    __syncthreads();
    s = red[0] + red[1] + red[2] + red[3];
    q = red[4] + red[5] + red[6] + red[7];
    float mean = s * (1.0f / DM);
    float var = q * (1.0f / DM) - mean * mean;
    float rstd = rsqrtf(var + 1e-5f);
    ushort4 o;
    o.x = f2bf_n((v[0]-mean)*rstd*g2[t*4+0] + beta2[t*4+0]);
    o.y = f2bf_n((v[1]-mean)*rstd*g2[t*4+1] + beta2[t*4+1]);
    o.z = f2bf_n((v[2]-mean)*rstd*g2[t*4+2] + beta2[t*4+2]);
    o.w = f2bf_n((v[3]-mean)*rstd*g2[t*4+3] + beta2[t*4+3]);
    *reinterpret_cast<ushort4*>(&hout[(size_t)r * DM + t * 4]) = o;
}

// ---------------- MFMA GEMM, double-buffered; 3-way pointer select via blockIdx.z ----
// MODE: 0 ->bf16; 1 +resid->bf16; 2 gelu2->bf16; 3 +bias+resid->f32; 4 accum->f32
#define TBM 64
#define TBN 128
#define TBK 64
#define ROWA 72
#define ROWB 72

template<int MODE>
__global__ __launch_bounds__(256) void mfma_gemm(
    const unsigned short* __restrict__ A,
    const float* __restrict__ Wa, const float* __restrict__ Wb, const float* __restrict__ Wc,
    const float* __restrict__ ba, const float* __restrict__ bbb, const float* __restrict__ bc,
    const unsigned short* __restrict__ resid,
    unsigned short* __restrict__ oa, unsigned short* __restrict__ ob,
    unsigned short* __restrict__ oc,
    float* __restrict__ outF,
    int M, int N, int K, int ldw)
{
    const int sel = blockIdx.z;
    const float* W = (sel == 0) ? Wa : (sel == 1) ? Wb : Wc;
    const float* bias = (sel == 0) ? ba : (sel == 1) ? bbb : bc;
    unsigned short* outB = (sel == 0) ? oa : (sel == 1) ? ob : oc;

    __shared__ unsigned short As[2][TBM * ROWA];
    __shared__ unsigned short Bs[2][TBN * ROWB];
    const int t = threadIdx.x;
    const int lane = t & 63;
    const int w = t >> 6, wm = w >> 1, wn = w & 1;
    const int l15 = lane & 15, l4 = lane >> 4;
    const int m0 = blockIdx.y * TBM, n0 = blockIdx.x * TBN;

    f32x4 acc[2][4];
    #pragma unroll
    for (int i = 0; i < 2; ++i)
        #pragma unroll
        for (int j = 0; j < 4; ++j)
            #pragma unroll
            for (int r = 0; r < 4; ++r) acc[i][j][r] = 0.0f;

    const int ar = t >> 2, aseg = t & 3;
    const unsigned short* aG = A + (size_t)(m0 + ar) * K + aseg * 16;
    const int aLo = ar * ROWA + aseg * 16;
    const int bn = t & 127, bb0 = t >> 7;
    const float* wG = W + (n0 + bn);
    const int bswz = bn & 7;
    const int bLo = bn * ROWB;

    u16x8 a0, a1;
    float wv[4][8];
    // prologue: tile 0 load + stage
    a0 = *(const u16x8*)(aG);
    a1 = *(const u16x8*)(aG + 8);
    #pragma unroll
    for (int b = 0; b < 4; ++b)
        #pragma unroll
        for (int j = 0; j < 8; ++j)
            wv[b][j] = wG[(size_t)((bb0 + 2 * b) * 8 + j) * ldw];
    *(u16x8*)&As[0][aLo] = a0;
    *(u16x8*)&As[0][aLo + 8] = a1;
    #pragma unroll
    for (int b = 0; b < 4; ++b) {
        u16x8 bv;
        #pragma unroll
        for (int j = 0; j < 8; ++j) bv[j] = f2bf_n(wv[b][j]);
        *(u16x8*)&Bs[0][bLo + (((bb0 + 2 * b) ^ bswz) * 8)] = bv;
    }
    __syncthreads();

    const int NT = K / TBK;
    for (int kt = 0; kt < NT; ++kt) {
        const int cur = kt & 1;
        if (kt + 1 < NT) {
            const int k0 = (kt + 1) * TBK;
            a0 = *(const u16x8*)(aG + k0);
            a1 = *(const u16x8*)(aG + k0 + 8);
            #pragma unroll
            for (int b = 0; b < 4; ++b)
                #pragma unroll
                for (int j = 0; j < 8; ++j)
                    wv[b][j] = wG[(size_t)(k0 + (bb0 + 2 * b) * 8 + j) * ldw];
        }
        #pragma unroll
        for (int kk = 0; kk < 2; ++kk) {
            bf16x8 af[2], bfr[4];
            #pragma unroll
            for (int mt = 0; mt < 2; ++mt) {
                u16x8 tmp = *(const u16x8*)&As[cur][(wm*32 + mt*16 + l15) * ROWA + kk*32 + l4*8];
                af[mt] = __builtin_bit_cast(bf16x8, tmp);
            }
            #pragma unroll
            for (int nt = 0; nt < 4; ++nt) {
                const int n = wn*64 + nt*16 + l15;
                const int blk = kk*4 + l4;
                u16x8 tmp = *(const u16x8*)&Bs[cur][n * ROWB + ((blk ^ (n & 7)) * 8)];
                bfr[nt] = __builtin_bit_cast(bf16x8, tmp);
            }
            #pragma unroll
            for (int mt = 0; mt < 2; ++mt)
                #pragma unroll
                for (int nt = 0; nt < 4; ++nt)
                    acc[mt][nt] = __builtin_amdgcn_mfma_f32_16x16x32_bf16(
                        af[mt], bfr[nt], acc[mt][nt], 0, 0, 0);
        }
        if (kt + 1 < NT) {
            __syncthreads();
            const int nx = cur ^ 1;
            *(u16x8*)&As[nx][aLo] = a0;
            *(u16x8*)&As[nx][aLo + 8] = a1;
            #pragma unroll
            for (int b = 0; b < 4; ++b) {
                u16x8 bv;
                #pragma unroll
                for (int j = 0; j < 8; ++j) bv[j] = f2bf_n(wv[b][j]);
                *(u16x8*)&Bs[nx][bLo + (((bb0 + 2 * b) ^ bswz) * 8)] = bv;
            }
            __syncthreads();
        }
    }

    #pragma unroll
    for (int mt = 0; mt < 2; ++mt) {
        const int mbase = m0 + wm*32 + mt*16 + l4*4;
        #pragma unroll
        for (int nt = 0; nt < 4; ++nt) {
            const int n = n0 + wn*64 + nt*16 + l15;
            const float bs = (MODE == 4) ? 0.0f : bias[n];
            #pragma unroll
            for (int r = 0; r < 4; ++r) {
                const int m = mbase + r;
                float v = acc[mt][nt][r] + bs;
                if (MODE == 2) v = v / (1.0f + expf(-1.702f * v));
                if (MODE == 1 || MODE == 3) v += bf2f(resid[(size_t)m * N + n]);
                if (MODE == 3)      outF[(size_t)m * N + n] = v;
                else if (MODE == 4) outF[(size_t)m * N + n] += v;
                else                outB[(size_t)m * N + n] = f2bf_n(v);
            }
        }
    }
}

// ---------------- MFMA flash attention (bias folded into MFMA C-in) ----------------
#define AKT 128
#define KROW 72
#define VROW 136
#define PROW 136

__global__ __launch_bounds__(256) void attn_mfma(const unsigned short* __restrict__ qbuf,
                                                 const unsigned short* __restrict__ kbuf,
                                                 const unsigned short* __restrict__ vbuf,
                                                 const float* __restrict__ attb,
                                                 const int* __restrict__ mask,
                                                 unsigned short* __restrict__ ctx) {
    __shared__ unsigned short Ks[AKT * KROW];
    __shared__ unsigned short Vt[DH * VROW];
    __shared__ unsigned short Pb[4 * 16 * PROW];
    const int t = threadIdx.x;
    const int lane = t & 63;
    const int w = t >> 6;
    const int l15 = lane & 15, l4 = lane >> 4;
    const int q0 = blockIdx.x * 64;
    const int h = blockIdx.y;
    const int b = blockIdx.z;

    bf16x8 qf[2];
    {
        const unsigned short* qrow = qbuf + ((size_t)(b * SEQ + q0 + w * 16 + l15)) * DM + h * DH;
        u16x8 t0 = *(const u16x8*)(qrow + l4 * 8);
        u16x8 t1 = *(const u16x8*)(qrow + 32 + l4 * 8);
        qf[0] = __builtin_bit_cast(bf16x8, t0);
        qf[1] = __builtin_bit_cast(bf16x8, t1);
    }

    float m[4] = {-1e30f, -1e30f, -1e30f, -1e30f};
    float l[4] = {0.0f, 0.0f, 0.0f, 0.0f};
    f32x4 o[4];
    #pragma unroll
    for (int dt = 0; dt < 4; ++dt)
        #pragma unroll
        for (int r = 0; r < 4; ++r) o[dt][r] = 0.0f;

    unsigned short* Pw = Pb + w * 16 * PROW;

    for (int kt = 0; kt < SEQ / AKT; ++kt) {
        const int kbase = kt * AKT;
        const float* bptr = attb + (((size_t)(b * NH + h)) * SEQ + (q0 + w * 16)) * SEQ + kbase;
        const int* mptr = mask + ((size_t)(b * SEQ) + q0 + w * 16) * SEQ + kbase;

        // bias folded into MFMA C-in: acc = 8*bias (loads issue before staging)
        f32x4 acc[8];
        int mk[8][4];
        #pragma unroll
        for (int nt = 0; nt < 8; ++nt)
            #pragma unroll
            for (int r = 0; r < 4; ++r) {
                acc[nt][r] = 8.0f * bptr[(size_t)(l4 * 4 + r) * SEQ + nt * 16 + l15];
                mk[nt][r] = mptr[(size_t)(l4 * 4 + r) * SEQ + nt * 16 + l15];
            }

        __syncthreads();
        {
            const int kr = t >> 1, c0 = (t & 1) * 32;
            const unsigned short* g = kbuf + ((size_t)(b * SEQ + kbase + kr)) * DM + h * DH + c0;
            u16x8 v0 = *(const u16x8*)(g);
            u16x8 v1 = *(const u16x8*)(g + 8);
            u16x8 v2 = *(const u16x8*)(g + 16);
            u16x8 v3 = *(const u16x8*)(g + 24);
            unsigned short* s = Ks + kr * KROW + c0;
            *(u16x8*)s = v0; *(u16x8*)(s + 8) = v1;
            *(u16x8*)(s + 16) = v2; *(u16x8*)(s + 24) = v3;
        }
        {
            const int kp = t & 63;
            unsigned int* vt32 = (unsigned int*)Vt;
            #pragma unroll
            for (int g8 = (t >> 6); g8 < 8; g8 += 4) {
                const unsigned short* ga =
                    vbuf + ((size_t)(b * SEQ + kbase + 2 * kp)) * DM + h * DH + g8 * 8;
                u16x8 va = *(const u16x8*)ga;
                u16x8 vb = *(const u16x8*)(ga + DM);
                #pragma unroll
                for (int j = 0; j < 8; ++j) {
                    const int d = g8 * 8 + j;
                    vt32[d * (VROW / 2) + kp] =
                        (unsigned int)va[j] | ((unsigned int)vb[j] << 16);
                }
            }
        }
        __syncthreads();

        #pragma unroll
        for (int kk = 0; kk < 2; ++kk) {
            #pragma unroll
            for (int nt = 0; nt < 8; ++nt) {
                u16x8 tmp = *(const u16x8*)(Ks + (nt * 16 + l15) * KROW + kk * 32 + l4 * 8);
                acc[nt] = __builtin_amdgcn_mfma_f32_16x16x32_bf16(
                    qf[kk], __builtin_bit_cast(bf16x8, tmp), acc[nt], 0, 0, 0);
            }
        }

        float pm[4] = {-1e30f, -1e30f, -1e30f, -1e30f};
        #pragma unroll
        for (int nt = 0; nt < 8; ++nt) {
            #pragma unroll
            for (int r = 0; r < 4; ++r) {
                float sv = acc[nt][r] * 0.125f;
                if (mk[nt][r]) sv = -1e30f;
                acc[nt][r] = sv;
                pm[r] = fmaxf(pm[r], sv);
            }
        }
        #pragma unroll
        for (int r = 0; r < 4; ++r) {
            #pragma unroll
            for (int off = 1; off < 16; off <<= 1)
                pm[r] = fmaxf(pm[r], __shfl_xor(pm[r], off));
        }
        float al[4], ps[4];
        #pragma unroll
        for (int r = 0; r < 4; ++r) {
            const float mn = fmaxf(m[r], pm[r]);
            al[r] = __expf(m[r] - mn);
            m[r] = mn;
            ps[r] = 0.0f;
        }
        #pragma unroll
        for (int nt = 0; nt < 8; ++nt) {
            #pragma unroll
            for (int r = 0; r < 4; ++r) {
                const float p = __expf(acc[nt][r] - m[r]);
                acc[nt][r] = p;
                ps[r] += p;
            }
        }
        #pragma unroll
        for (int r = 0; r < 4; ++r) {
            #pragma unroll
            for (int off = 1; off < 16; off <<= 1) ps[r] += __shfl_xor(ps[r], off);
            l[r] = l[r] * al[r] + ps[r];
        }
        #pragma unroll
        for (int dt = 0; dt < 4; ++dt)
            #pragma unroll
            for (int r = 0; r < 4; ++r) o[dt][r] *= al[r];

        #pragma unroll
        for (int nt = 0; nt < 8; ++nt)
            #pragma unroll
            for (int r = 0; r < 4; ++r)
                Pw[(l4 * 4 + r) * PROW + nt * 16 + l15] = f2bf_n(acc[nt][r]);

        #pragma unroll
        for (int ks = 0; ks < 4; ++ks) {
            u16x8 pa = *(const u16x8*)(Pw + l15 * PROW + ks * 32 + l4 * 8);
            #pragma unroll
            for (int dt = 0; dt < 4; ++dt) {
                u16x8 vv = *(const u16x8*)(Vt + (dt * 16 + l15) * VROW + ks * 32 + l4 * 8);
                o[dt] = __builtin_amdgcn_mfma_f32_16x16x32_bf16(
                    __builtin_bit_cast(bf16x8, pa), __builtin_bit_cast(bf16x8, vv),
                    o[dt], 0, 0, 0);
            }
        }
    }

    #pragma unroll
    for (int r = 0; r < 4; ++r) {
        const float inv = 1.0f / l[r];
        const size_t row = (size_t)(b * SEQ + q0 + w * 16 + l4 * 4 + r) * DM + h * DH;
        #pragma unroll
        for (int dt = 0; dt < 4; ++dt)
            ctx[row + dt * 16 + l15] = f2bf_n(o[dt][r] * inv);
    }
}

// ---------------- host launch ----------------
extern "C" void kernel_launch(void* const* d_in, const int* in_sizes, int n_in,
                              void* d_out, int out_size, void* d_ws, size_t ws_size,
                              hipStream_t stream) {
    const float* src  = (const float*)d_in[0];
    const int*   mask = (const int*)d_in[1];
    const int*   ts   = (const int*)d_in[2];
    const float* attb = (const float*)d_in[3];
    const float* Wada = (const float*)d_in[4];
    const float* bada = (const float*)d_in[5];
    const float* Wq   = (const float*)d_in[6];
    const float* bq   = (const float*)d_in[7];
    const float* Wk   = (const float*)d_in[8];
    const float* bk   = (const float*)d_in[9];
    const float* Wv   = (const float*)d_in[10];
    const float* bv   = (const float*)d_in[11];
    const float* Wo   = (const float*)d_in[12];
    const float* bo   = (const float*)d_in[13];
    const float* W1   = (const float*)d_in[14];
    const float* b1   = (const float*)d_in[15];
    const float* W2   = (const float*)d_in[16];
    const float* b2   = (const float*)d_in[17];
    const float* g2   = (const float*)d_in[18];
    const float* bt2  = (const float*)d_in[19];
    float* out = (float*)d_out;

    const size_t MB = 1024 * 1024;
    const size_t NEED = 65536 + 12 * MB;
    if (ws_size < NEED) {
        fill0_kernel<<<(size_t)MROWS * DM / 256, 256, 0, stream>>>(out);
        return;
    }

    char* ws = (char*)d_ws;
    float* semb = (float*)(ws + 4096);
    float* ss   = (float*)(ws + 24576);
    char*  base = ws + 65536;
    unsigned short* slotA = (unsigned short*)(base);            // xb -> mid
    unsigned short* slotB = (unsigned short*)(base + 4 * MB);   // qb -> x2
    unsigned short* slotC = (unsigned short*)(base + 8 * MB);   // kb -> h
    unsigned short* vb   = (unsigned short*)d_out;               // 4 MB
    unsigned short* ctxb = (unsigned short*)((char*)d_out + 4 * MB);
    unsigned short* xb = slotA;
    unsigned short* qb = slotB;
    unsigned short* kb = slotC;
    unsigned short* x2 = slotB;
    unsigned short* hb = slotC;
    unsigned short* mid = slotA;
    float* adap = (float*)slotC;  // 1 MB ada partials (slotC free pre-adaln)

    semb_kernel<<<4, 256, 0, stream>>>(ts, semb);
    ada_part_kernel<<<dim3(16, 16), 256, 0, stream>>>(semb, Wada, adap);
    ada_red_kernel<<<32, 256, 0, stream>>>(adap, bada, ss);
    adaln_kernel<<<MROWS, 256, 0, stream>>>(src, ss, xb);

    // fused QKV: grid.z selects weight/bias/out
    mfma_gemm<0><<<dim3(8, 32, 3), 256, 0, stream>>>(xb, Wq, Wk, Wv, bq, bk, bv, nullptr,
                                                     qb, kb, vb, nullptr, MROWS, DM, DM, DM);
    attn_mfma<<<dim3(SEQ / 64, NH, BATCH), 256, 0, stream>>>(qb, kb, vb, attb, mask, ctxb);
    // x2 = xb + ctx@Wo + bo
    mfma_gemm<1><<<dim3(8, 32), 256, 0, stream>>>(ctxb, Wo, Wo, Wo, bo, bo, bo, xb,
                                                  x2, x2, x2, nullptr, MROWS, DM, DM, DM);
    ln2_kernel<<<MROWS, 256, 0, stream>>>(x2, g2, bt2, hb);
    // FFN: 4 N-chunks of W1 -> mid; W2 K-chunk partials accumulate into f32 out
    for (int nc = 0; nc < 4; ++nc) {
        const float* w1c = W1 + nc * 1024;
        const float* b1c = b1 + nc * 1024;
        mfma_gemm<2><<<dim3(8, 32), 256, 0, stream>>>(hb, w1c, w1c, w1c, b1c, b1c, b1c, nullptr,
                                                      mid, mid, mid, nullptr,
                                                      MROWS, DM, DM, DFF);
        const float* w2c = W2 + (size_t)nc * 1024 * DM;
        if (nc == 0)
            mfma_gemm<3><<<dim3(8, 32), 256, 0, stream>>>(mid, w2c, w2c, w2c, b2, b2, b2, x2,
                                                          nullptr, nullptr, nullptr, out,
                                                          MROWS, DM, DM, DM);
        else
            mfma_gemm<4><<<dim3(8, 32), 256, 0, stream>>>(mid, w2c, w2c, w2c,
                                                          nullptr, nullptr, nullptr, nullptr,
                                                          nullptr, nullptr, nullptr, out,
                                                          MROWS, DM, DM, DM);
    }
}

// Round 11
// 248.398 us; speedup vs baseline: 1.3714x; 1.3714x over previous
//
#include <hip/hip_runtime.h>
#include <math.h>

typedef __bf16 bf16x8 __attribute__((ext_vector_type(8)));
typedef float  f32x4  __attribute__((ext_vector_type(4)));
typedef unsigned short u16x8 __attribute__((ext_vector_type(8)));

__device__ __forceinline__ float bf2f(unsigned short u) {
    return __uint_as_float(((unsigned int)u) << 16);
}
__device__ __forceinline__ unsigned short f2bf_n(float f) {
    return __builtin_bit_cast(unsigned short, (__bf16)f);  // native cvt (RNE)
}

// dims
#define BATCH 4
#define SEQ 512
#define DM 1024
#define NH 16
#define DH 64
#define DFF 4096
#define MROWS (BATCH * SEQ)   // 2048

__global__ __launch_bounds__(256) void fill0_kernel(float* __restrict__ out) {
    out[blockIdx.x * 256 + threadIdx.x] = 0.0f;
}

// ---------------- weight transpose+convert: in[K][N] f32 -> out[N][K] bf16 ----------
__global__ __launch_bounds__(256) void tconv_kernel(const float* __restrict__ in,
                                                    unsigned short* __restrict__ out,
                                                    int K, int N) {
    __shared__ float tile[32][33];
    const int n0 = blockIdx.x * 32, k0 = blockIdx.y * 32;
    const int tx = threadIdx.x & 31, ty = threadIdx.x >> 5;  // ty 0..7
    #pragma unroll
    for (int i = 0; i < 32; i += 8)
        tile[ty + i][tx] = in[(size_t)(k0 + ty + i) * N + n0 + tx];
    __syncthreads();
    #pragma unroll
    for (int i = 0; i < 32; i += 8)
        out[(size_t)(n0 + ty + i) * K + k0 + tx] = f2bf_n(tile[tx][ty + i]);
}

// ---------------- 1) sinusoidal emb + silu ----------------
__global__ void semb_kernel(const int* __restrict__ ts, float* __restrict__ semb) {
    int b = blockIdx.x;
    float x = (float)ts[b] * 40.0f;
    for (int j = threadIdx.x; j < 1024; j += 256) {
        int idx = (j < 512) ? j : (j - 512);
        float fr = expf(-9.210340371976184f * (float)idx / 511.0f);
        float e = x * fr;
        float v = (j < 512) ? sinf(e) : cosf(e);
        semb[b * 1024 + j] = v / (1.0f + expf(-v));
    }
}

// ---------------- 2a) ada partials ----------------
__global__ __launch_bounds__(256) void ada_part_kernel(const float* __restrict__ semb,
                                                       const float* __restrict__ W,
                                                       float* __restrict__ part) {
    const int nb = blockIdx.x, kc = blockIdx.y;
    const int t = threadIdx.x;
    __shared__ float e_s[4][64];
    e_s[t >> 6][t & 63] = semb[(t >> 6) * 1024 + kc * 64 + (t & 63)];
    __syncthreads();
    const int n = nb * 128 + (t & 127);
    const int half = t >> 7;
    float a0 = 0.f, a1 = 0.f, a2 = 0.f, a3 = 0.f;
    const int kk0 = half * 32;
    #pragma unroll 8
    for (int kk = kk0; kk < kk0 + 32; ++kk) {
        const float w = W[(size_t)(kc * 64 + kk) * 2048 + n];
        a0 += e_s[0][kk] * w; a1 += e_s[1][kk] * w;
        a2 += e_s[2][kk] * w; a3 += e_s[3][kk] * w;
    }
    const int j = kc * 2 + half;
    float* p = part + (size_t)j * 4 * 2048 + n;
    p[0] = a0; p[2048] = a1; p[2 * 2048] = a2; p[3 * 2048] = a3;
}

// ---------------- 2b) ada reduce ----------------
__global__ __launch_bounds__(256) void ada_red_kernel(const float* __restrict__ part,
                                                      const float* __restrict__ bias,
                                                      float* __restrict__ ss) {
    const int idx = blockIdx.x * 256 + threadIdx.x;
    const int b = idx >> 11, n = idx & 2047;
    float acc = bias[n];
    #pragma unroll 8
    for (int j = 0; j < 32; ++j) acc += part[((size_t)j * 4 + b) * 2048 + n];
    ss[b * 2048 + n] = acc;
}

// ---------------- 3) AdaLN ----------------
__global__ __launch_bounds__(256) void adaln_kernel(const float* __restrict__ src,
                                                    const float* __restrict__ ss,
                                                    unsigned short* __restrict__ xb) {
    int r = blockIdx.x;
    int b = r >> 9;
    int t = threadIdx.x;
    float4 v4 = *reinterpret_cast<const float4*>(&src[(size_t)r * DM + t * 4]);
    float v[4] = {v4.x, v4.y, v4.z, v4.w};
    float s = v[0] + v[1] + v[2] + v[3];
    float q = v[0]*v[0] + v[1]*v[1] + v[2]*v[2] + v[3]*v[3];
    #pragma unroll
    for (int off = 32; off > 0; off >>= 1) { s += __shfl_down(s, off); q += __shfl_down(q, off); }
    __shared__ float red[8];
    if ((t & 63) == 0) { red[t >> 6] = s; red[4 + (t >> 6)] = q; }
    __syncthreads();
    s = red[0] + red[1] + red[2] + red[3];
    q = red[4] + red[5] + red[6] + red[7];
    float mean = s * (1.0f / DM);
    float var = q * (1.0f / DM) - mean * mean;
    float rstd = rsqrtf(var + 1e-5f);
    ushort4 o;
    o.x = f2bf_n((v[0]-mean)*rstd*(1.0f+ss[b*2048 + t*4+0]) + ss[b*2048+1024 + t*4+0]);
    o.y = f2bf_n((v[1]-mean)*rstd*(1.0f+ss[b*2048 + t*4+1]) + ss[b*2048+1024 + t*4+1]);
    o.z = f2bf_n((v[2]-mean)*rstd*(1.0f+ss[b*2048 + t*4+2]) + ss[b*2048+1024 + t*4+2]);
    o.w = f2bf_n((v[3]-mean)*rstd*(1.0f+ss[b*2048 + t*4+3]) + ss[b*2048+1024 + t*4+3]);
    *reinterpret_cast<ushort4*>(&xb[(size_t)r * DM + t * 4]) = o;
}

// ---------------- LN2 ----------------
__global__ __launch_bounds__(256) void ln2_kernel(const unsigned short* __restrict__ x,
                                                  const float* __restrict__ g2,
                                                  const float* __restrict__ beta2,
                                                  unsigned short* __restrict__ hout) {
    int r = blockIdx.x;
    int t = threadIdx.x;
    ushort4 s4 = *reinterpret_cast<const ushort4*>(&x[(size_t)r * DM + t * 4]);
    float v[4] = {bf2f(s4.x), bf2f(s4.y), bf2f(s4.z), bf2f(s4.w)};
    float s = v[0] + v[1] + v[2] + v[3];
    float q = v[0]*v[0] + v[1]*v[1] + v[2]*v[2] + v[3]*v[3];
    #pragma unroll
    for (int off = 32; off > 0; off >>= 1) { s += __shfl_down(s, off); q += __shfl_down(q, off); }
    __shared__ float red[8];
    if ((t & 63) == 0) { red[t >> 6] = s; red[4 + (t >> 6)] = q; }
    __syncthreads();
    s = red[0] + red[1] + red[2] + red[3];
    q = red[4] + red[5] + red[6] + red[7];
    float mean = s * (1.0f / DM);
    float var = q * (1.0f / DM) - mean * mean;
    float rstd = rsqrtf(var + 1e-5f);
    ushort4 o;
    o.x = f2bf_n((v[0]-mean)*rstd*g2[t*4+0] + beta2[t*4+0]);
    o.y = f2bf_n((v[1]-mean)*rstd*g2[t*4+1] + beta2[t*4+1]);
    o.z = f2bf_n((v[2]-mean)*rstd*g2[t*4+2] + beta2[t*4+2]);
    o.w = f2bf_n((v[3]-mean)*rstd*g2[t*4+3] + beta2[t*4+3]);
    *reinterpret_cast<ushort4*>(&hout[(size_t)r * DM + t * 4]) = o;
}

// ================= NEW: bf16-weight GEMM (Wt[N][K] bf16), XCD-swizzled =================
// MODE: 0 ->bf16; 1 +resid->bf16; 2 gelu2->bf16; 3 +bias+resid->f32; 4 accum->f32
#define TBM 64
#define TBN 128
#define TBK 64
#define PIT 72   // LDS row pitch in ushorts (9 x 16B groups -> even bank-group spread)

template<int MODE>
__global__ __launch_bounds__(256) void gemm_bt(
    const unsigned short* __restrict__ A,
    const unsigned short* __restrict__ Wta, const unsigned short* __restrict__ Wtb,
    const unsigned short* __restrict__ Wtc,
    const float* __restrict__ ba, const float* __restrict__ bbb, const float* __restrict__ bc,
    const unsigned short* __restrict__ resid,
    unsigned short* __restrict__ oa, unsigned short* __restrict__ ob,
    unsigned short* __restrict__ oc,
    float* __restrict__ outF,
    int M, int N, int K, int ldk)
{
    // bijective XCD-chunked swizzle (nwg % 8 == 0 for all our grids)
    const int gx = gridDim.x, gy = gridDim.y;
    const int nwg = gx * gy * gridDim.z;
    const int wid = blockIdx.x + gx * (blockIdx.y + gy * blockIdx.z);
    const int aid = (wid & 7) * (nwg >> 3) + (wid >> 3);
    const int bx = aid % gx;
    const int by = (aid / gx) % gy;
    const int sel = aid / (gx * gy);

    const unsigned short* Wt = (sel == 0) ? Wta : (sel == 1) ? Wtb : Wtc;
    const float* bias = (sel == 0) ? ba : (sel == 1) ? bbb : bc;
    unsigned short* outB = (sel == 0) ? oa : (sel == 1) ? ob : oc;

    __shared__ unsigned short As[TBM * PIT];
    __shared__ unsigned short Bs[TBN * PIT];
    const int t = threadIdx.x;
    const int lane = t & 63;
    const int w = t >> 6, wm = w >> 1, wn = w & 1;
    const int l15 = lane & 15, l4 = lane >> 4;
    const int m0 = by * TBM, n0 = bx * TBN;

    f32x4 acc[2][4];
    #pragma unroll
    for (int i = 0; i < 2; ++i)
        #pragma unroll
        for (int j = 0; j < 4; ++j)
            #pragma unroll
            for (int r = 0; r < 4; ++r) acc[i][j][r] = 0.0f;

    // staging maps: A 64 rows x 4 segs of 16; B 128 rows x 2 segs of 32
    const int ar = t >> 2, aseg = (t & 3) * 16;
    const unsigned short* aG = A + (size_t)(m0 + ar) * K + aseg;
    unsigned short* aL = As + ar * PIT + aseg;
    const int br = t >> 1, bseg = (t & 1) * 32;
    const unsigned short* bG = Wt + (size_t)(n0 + br) * ldk + bseg;
    unsigned short* bL = Bs + br * PIT + bseg;

    u16x8 ra0, ra1, rb0, rb1, rb2, rb3;
    ra0 = *(const u16x8*)(aG);
    ra1 = *(const u16x8*)(aG + 8);
    rb0 = *(const u16x8*)(bG);
    rb1 = *(const u16x8*)(bG + 8);
    rb2 = *(const u16x8*)(bG + 16);
    rb3 = *(const u16x8*)(bG + 24);

    const int NT = K / TBK;
    for (int kt = 0; kt < NT; ++kt) {
        *(u16x8*)aL = ra0; *(u16x8*)(aL + 8) = ra1;
        *(u16x8*)bL = rb0; *(u16x8*)(bL + 8) = rb1;
        *(u16x8*)(bL + 16) = rb2; *(u16x8*)(bL + 24) = rb3;
        __syncthreads();
        if (kt + 1 < NT) {
            const int k0 = (kt + 1) * TBK;
            ra0 = *(const u16x8*)(aG + k0);
            ra1 = *(const u16x8*)(aG + k0 + 8);
            rb0 = *(const u16x8*)(bG + k0);
            rb1 = *(const u16x8*)(bG + k0 + 8);
            rb2 = *(const u16x8*)(bG + k0 + 16);
            rb3 = *(const u16x8*)(bG + k0 + 24);
        }
        #pragma unroll
        for (int kk = 0; kk < 2; ++kk) {
            bf16x8 af[2], bfr[4];
            #pragma unroll
            for (int mt = 0; mt < 2; ++mt) {
                u16x8 tmp = *(const u16x8*)(As + (wm*32 + mt*16 + l15) * PIT + kk*32 + l4*8);
                af[mt] = __builtin_bit_cast(bf16x8, tmp);
            }
            #pragma unroll
            for (int nt = 0; nt < 4; ++nt) {
                u16x8 tmp = *(const u16x8*)(Bs + (wn*64 + nt*16 + l15) * PIT + kk*32 + l4*8);
                bfr[nt] = __builtin_bit_cast(bf16x8, tmp);
            }
            #pragma unroll
            for (int mt = 0; mt < 2; ++mt)
                #pragma unroll
                for (int nt = 0; nt < 4; ++nt)
                    acc[mt][nt] = __builtin_amdgcn_mfma_f32_16x16x32_bf16(
                        af[mt], bfr[nt], acc[mt][nt], 0, 0, 0);
        }
        __syncthreads();
    }

    #pragma unroll
    for (int mt = 0; mt < 2; ++mt) {
        const int mbase = m0 + wm*32 + mt*16 + l4*4;
        #pragma unroll
        for (int nt = 0; nt < 4; ++nt) {
            const int n = n0 + wn*64 + nt*16 + l15;
            const float bs = (MODE == 4) ? 0.0f : bias[n];
            #pragma unroll
            for (int r = 0; r < 4; ++r) {
                const int m = mbase + r;
                float v = acc[mt][nt][r] + bs;
                if (MODE == 2) v = v / (1.0f + expf(-1.702f * v));
                if (MODE == 1 || MODE == 3) v += bf2f(resid[(size_t)m * N + n]);
                if (MODE == 3)      outF[(size_t)m * N + n] = v;
                else if (MODE == 4) outF[(size_t)m * N + n] += v;
                else                outB[(size_t)m * N + n] = f2bf_n(v);
            }
        }
    }
}

// ================= fallback GEMM (round-10, proven) =================
#define ROWA 72
#define ROWB 72
template<int MODE>
__global__ __launch_bounds__(256) void mfma_gemm(
    const unsigned short* __restrict__ A,
    const float* __restrict__ Wa, const float* __restrict__ Wb, const float* __restrict__ Wc,
    const float* __restrict__ ba, const float* __restrict__ bbb, const float* __restrict__ bc,
    const unsigned short* __restrict__ resid,
    unsigned short* __restrict__ oa, unsigned short* __restrict__ ob,
    unsigned short* __restrict__ oc,
    float* __restrict__ outF,
    int M, int N, int K, int ldw)
{
    const int sel = blockIdx.z;
    const float* W = (sel == 0) ? Wa : (sel == 1) ? Wb : Wc;
    const float* bias = (sel == 0) ? ba : (sel == 1) ? bbb : bc;
    unsigned short* outB = (sel == 0) ? oa : (sel == 1) ? ob : oc;

    __shared__ unsigned short As[TBM * ROWA];
    __shared__ unsigned short Bs[TBN * ROWB];
    const int t = threadIdx.x;
    const int lane = t & 63;
    const int w = t >> 6, wm = w >> 1, wn = w & 1;
    const int l15 = lane & 15, l4 = lane >> 4;
    const int m0 = blockIdx.y * TBM, n0 = blockIdx.x * TBN;

    f32x4 acc[2][4];
    #pragma unroll
    for (int i = 0; i < 2; ++i)
        #pragma unroll
        for (int j = 0; j < 4; ++j)
            #pragma unroll
            for (int r = 0; r < 4; ++r) acc[i][j][r] = 0.0f;

    const int ar = t >> 2, aseg = t & 3;
    const unsigned short* aG = A + (size_t)(m0 + ar) * K + aseg * 16;
    unsigned short* aL = As + ar * ROWA + aseg * 16;
    const int bn = t & 127, bb0 = t >> 7;
    const float* wG = W + (n0 + bn);
    unsigned short* bL = Bs + bn * ROWB;
    const int bswz = bn & 7;

    for (int k0 = 0; k0 < K; k0 += TBK) {
        u16x8 a0 = *(const u16x8*)(aG + k0);
        u16x8 a1 = *(const u16x8*)(aG + k0 + 8);
        float wv[4][8];
        #pragma unroll
        for (int b = 0; b < 4; ++b)
            #pragma unroll
            for (int j = 0; j < 8; ++j)
                wv[b][j] = wG[(size_t)(k0 + (bb0 + 2 * b) * 8 + j) * ldw];
        __syncthreads();
        *(u16x8*)aL = a0;
        *(u16x8*)(aL + 8) = a1;
        #pragma unroll
        for (int b = 0; b < 4; ++b) {
            u16x8 bv;
            #pragma unroll
            for (int j = 0; j < 8; ++j) bv[j] = f2bf_n(wv[b][j]);
            *(u16x8*)(bL + (((bb0 + 2 * b) ^ bswz) * 8)) = bv;
        }
        __syncthreads();
        #pragma unroll
        for (int kk = 0; kk < 2; ++kk) {
            bf16x8 af[2], bfr[4];
            #pragma unroll
            for (int mt = 0; mt < 2; ++mt) {
                u16x8 tmp = *(const u16x8*)&As[(wm*32 + mt*16 + l15) * ROWA + kk*32 + l4*8];
                af[mt] = __builtin_bit_cast(bf16x8, tmp);
            }
            #pragma unroll
            for (int nt = 0; nt < 4; ++nt) {
                const int n = wn*64 + nt*16 + l15;
                const int blk = kk*4 + l4;
                u16x8 tmp = *(const u16x8*)&Bs[n * ROWB + ((blk ^ (n & 7)) * 8)];
                bfr[nt] = __builtin_bit_cast(bf16x8, tmp);
            }
            #pragma unroll
            for (int mt = 0; mt < 2; ++mt)
                #pragma unroll
                for (int nt = 0; nt < 4; ++nt)
                    acc[mt][nt] = __builtin_amdgcn_mfma_f32_16x16x32_bf16(
                        af[mt], bfr[nt], acc[mt][nt], 0, 0, 0);
        }
    }

    #pragma unroll
    for (int mt = 0; mt < 2; ++mt) {
        const int mbase = m0 + wm*32 + mt*16 + l4*4;
        #pragma unroll
        for (int nt = 0; nt < 4; ++nt) {
            const int n = n0 + wn*64 + nt*16 + l15;
            const float bs = (MODE == 4) ? 0.0f : bias[n];
            #pragma unroll
            for (int r = 0; r < 4; ++r) {
                const int m = mbase + r;
                float v = acc[mt][nt][r] + bs;
                if (MODE == 2) v = v / (1.0f + expf(-1.702f * v));
                if (MODE == 1 || MODE == 3) v += bf2f(resid[(size_t)m * N + n]);
                if (MODE == 3)      outF[(size_t)m * N + n] = v;
                else if (MODE == 4) outF[(size_t)m * N + n] += v;
                else                outB[(size_t)m * N + n] = f2bf_n(v);
            }
        }
    }
}

// ---------------- MFMA flash attention (verified) ----------------
#define AKT 128
#define KROW 72
#define VROW 136
#define PROW 136

__global__ __launch_bounds__(256) void attn_mfma(const unsigned short* __restrict__ qbuf,
                                                 const unsigned short* __restrict__ kbuf,
                                                 const unsigned short* __restrict__ vbuf,
                                                 const float* __restrict__ attb,
                                                 const int* __restrict__ mask,
                                                 unsigned short* __restrict__ ctx) {
    __shared__ unsigned short Ks[AKT * KROW];
    __shared__ unsigned short Vt[DH * VROW];
    __shared__ unsigned short Pb[4 * 16 * PROW];
    const int t = threadIdx.x;
    const int lane = t & 63;
    const int w = t >> 6;
    const int l15 = lane & 15, l4 = lane >> 4;
    const int q0 = blockIdx.x * 64;
    const int h = blockIdx.y;
    const int b = blockIdx.z;

    bf16x8 qf[2];
    {
        const unsigned short* qrow = qbuf + ((size_t)(b * SEQ + q0 + w * 16 + l15)) * DM + h * DH;
        u16x8 t0 = *(const u16x8*)(qrow + l4 * 8);
        u16x8 t1 = *(const u16x8*)(qrow + 32 + l4 * 8);
        qf[0] = __builtin_bit_cast(bf16x8, t0);
        qf[1] = __builtin_bit_cast(bf16x8, t1);
    }

    float m[4] = {-1e30f, -1e30f, -1e30f, -1e30f};
    float l[4] = {0.0f, 0.0f, 0.0f, 0.0f};
    f32x4 o[4];
    #pragma unroll
    for (int dt = 0; dt < 4; ++dt)
        #pragma unroll
        for (int r = 0; r < 4; ++r) o[dt][r] = 0.0f;

    unsigned short* Pw = Pb + w * 16 * PROW;

    for (int kt = 0; kt < SEQ / AKT; ++kt) {
        const int kbase = kt * AKT;
        const float* bptr = attb + (((size_t)(b * NH + h)) * SEQ + (q0 + w * 16)) * SEQ + kbase;
        const int* mptr = mask + ((size_t)(b * SEQ) + q0 + w * 16) * SEQ + kbase;

        f32x4 acc[8];
        int mk[8][4];
        #pragma unroll
        for (int nt = 0; nt < 8; ++nt)
            #pragma unroll
            for (int r = 0; r < 4; ++r) {
                acc[nt][r] = 8.0f * bptr[(size_t)(l4 * 4 + r) * SEQ + nt * 16 + l15];
                mk[nt][r] = mptr[(size_t)(l4 * 4 + r) * SEQ + nt * 16 + l15];
            }

        __syncthreads();
        {
            const int kr = t >> 1, c0 = (t & 1) * 32;
            const unsigned short* g = kbuf + ((size_t)(b * SEQ + kbase + kr)) * DM + h * DH + c0;
            u16x8 v0 = *(const u16x8*)(g);
            u16x8 v1 = *(const u16x8*)(g + 8);
            u16x8 v2 = *(const u16x8*)(g + 16);
            u16x8 v3 = *(const u16x8*)(g + 24);
            unsigned short* s = Ks + kr * KROW + c0;
            *(u16x8*)s = v0; *(u16x8*)(s + 8) = v1;
            *(u16x8*)(s + 16) = v2; *(u16x8*)(s + 24) = v3;
        }
        {
            const int kp = t & 63;
            unsigned int* vt32 = (unsigned int*)Vt;
            #pragma unroll
            for (int g8 = (t >> 6); g8 < 8; g8 += 4) {
                const unsigned short* ga =
                    vbuf + ((size_t)(b * SEQ + kbase + 2 * kp)) * DM + h * DH + g8 * 8;
                u16x8 va = *(const u16x8*)ga;
                u16x8 vb = *(const u16x8*)(ga + DM);
                #pragma unroll
                for (int j = 0; j < 8; ++j) {
                    const int d = g8 * 8 + j;
                    vt32[d * (VROW / 2) + kp] =
                        (unsigned int)va[j] | ((unsigned int)vb[j] << 16);
                }
            }
        }
        __syncthreads();

        #pragma unroll
        for (int kk = 0; kk < 2; ++kk) {
            #pragma unroll
            for (int nt = 0; nt < 8; ++nt) {
                u16x8 tmp = *(const u16x8*)(Ks + (nt * 16 + l15) * KROW + kk * 32 + l4 * 8);
                acc[nt] = __builtin_amdgcn_mfma_f32_16x16x32_bf16(
                    qf[kk], __builtin_bit_cast(bf16x8, tmp), acc[nt], 0, 0, 0);
            }
        }

        float pm[4] = {-1e30f, -1e30f, -1e30f, -1e30f};
        #pragma unroll
        for (int nt = 0; nt < 8; ++nt) {
            #pragma unroll
            for (int r = 0; r < 4; ++r) {
                float sv = acc[nt][r] * 0.125f;
                if (mk[nt][r]) sv = -1e30f;
                acc[nt][r] = sv;
                pm[r] = fmaxf(pm[r], sv);
            }
        }
        #pragma unroll
        for (int r = 0; r < 4; ++r) {
            #pragma unroll
            for (int off = 1; off < 16; off <<= 1)
                pm[r] = fmaxf(pm[r], __shfl_xor(pm[r], off));
        }
        float al[4], ps[4];
        #pragma unroll
        for (int r = 0; r < 4; ++r) {
            const float mn = fmaxf(m[r], pm[r]);
            al[r] = __expf(m[r] - mn);
            m[r] = mn;
            ps[r] = 0.0f;
        }
        #pragma unroll
        for (int nt = 0; nt < 8; ++nt) {
            #pragma unroll
            for (int r = 0; r < 4; ++r) {
                const float p = __expf(acc[nt][r] - m[r]);
                acc[nt][r] = p;
                ps[r] += p;
            }
        }
        #pragma unroll
        for (int r = 0; r < 4; ++r) {
            #pragma unroll
            for (int off = 1; off < 16; off <<= 1) ps[r] += __shfl_xor(ps[r], off);
            l[r] = l[r] * al[r] + ps[r];
        }
        #pragma unroll
        for (int dt = 0; dt < 4; ++dt)
            #pragma unroll
            for (int r = 0; r < 4; ++r) o[dt][r] *= al[r];

        #pragma unroll
        for (int nt = 0; nt < 8; ++nt)
            #pragma unroll
            for (int r = 0; r < 4; ++r)
                Pw[(l4 * 4 + r) * PROW + nt * 16 + l15] = f2bf_n(acc[nt][r]);

        #pragma unroll
        for (int ks = 0; ks < 4; ++ks) {
            u16x8 pa = *(const u16x8*)(Pw + l15 * PROW + ks * 32 + l4 * 8);
            #pragma unroll
            for (int dt = 0; dt < 4; ++dt) {
                u16x8 vv = *(const u16x8*)(Vt + (dt * 16 + l15) * VROW + ks * 32 + l4 * 8);
                o[dt] = __builtin_amdgcn_mfma_f32_16x16x32_bf16(
                    __builtin_bit_cast(bf16x8, pa), __builtin_bit_cast(bf16x8, vv),
                    o[dt], 0, 0, 0);
            }
        }
    }

    #pragma unroll
    for (int r = 0; r < 4; ++r) {
        const float inv = 1.0f / l[r];
        const size_t row = (size_t)(b * SEQ + q0 + w * 16 + l4 * 4 + r) * DM + h * DH;
        #pragma unroll
        for (int dt = 0; dt < 4; ++dt)
            ctx[row + dt * 16 + l15] = f2bf_n(o[dt][r] * inv);
    }
}

// ---------------- host launch ----------------
extern "C" void kernel_launch(void* const* d_in, const int* in_sizes, int n_in,
                              void* d_out, int out_size, void* d_ws, size_t ws_size,
                              hipStream_t stream) {
    const float* src  = (const float*)d_in[0];
    const int*   mask = (const int*)d_in[1];
    const int*   ts   = (const int*)d_in[2];
    const float* attb = (const float*)d_in[3];
    const float* Wada = (const float*)d_in[4];
    const float* bada = (const float*)d_in[5];
    const float* Wq   = (const float*)d_in[6];
    const float* bq   = (const float*)d_in[7];
    const float* Wk   = (const float*)d_in[8];
    const float* bk   = (const float*)d_in[9];
    const float* Wv   = (const float*)d_in[10];
    const float* bv   = (const float*)d_in[11];
    const float* Wo   = (const float*)d_in[12];
    const float* bo   = (const float*)d_in[13];
    const float* W1   = (const float*)d_in[14];
    const float* b1   = (const float*)d_in[15];
    const float* W2   = (const float*)d_in[16];
    const float* b2   = (const float*)d_in[17];
    const float* g2   = (const float*)d_in[18];
    const float* bt2  = (const float*)d_in[19];
    float* out = (float*)d_out;

    const size_t MB = 1024 * 1024;
    const size_t NEED = 65536 + 12 * MB;
    const size_t NEED_BIG = 65536 + 36 * MB;
    if (ws_size < NEED) {
        fill0_kernel<<<(size_t)MROWS * DM / 256, 256, 0, stream>>>(out);
        return;
    }
    const bool BIG = (ws_size >= NEED_BIG);

    char* ws = (char*)d_ws;
    float* semb = (float*)(ws + 4096);
    float* ss   = (float*)(ws + 24576);
    char*  base = ws + 65536;
    unsigned short* slotA = (unsigned short*)(base);            // xb -> mid
    unsigned short* slotB = (unsigned short*)(base + 4 * MB);   // qb -> x2
    unsigned short* slotC = (unsigned short*)(base + 8 * MB);   // kb -> h
    unsigned short* vb   = (unsigned short*)d_out;
    unsigned short* ctxb = (unsigned short*)((char*)d_out + 4 * MB);
    unsigned short* xb = slotA;
    unsigned short* qb = slotB;
    unsigned short* kb = slotC;
    unsigned short* x2 = slotB;
    unsigned short* hb = slotC;
    unsigned short* mid = slotA;
    float* adap = (float*)slotC;

    // bf16 transposed weights (big path)
    unsigned short* Wtq = (unsigned short*)(base + 12 * MB);
    unsigned short* Wtk = Wtq + 1024 * 1024;
    unsigned short* Wtv = Wtk + 1024 * 1024;
    unsigned short* Wto = Wtv + 1024 * 1024;
    unsigned short* Wt1 = Wto + 1024 * 1024;               // [4096][1024]
    unsigned short* Wt2 = Wt1 + (size_t)4096 * 1024;       // [1024][4096]

    if (BIG) {
        tconv_kernel<<<dim3(32, 32), 256, 0, stream>>>(Wq, Wtq, 1024, 1024);
        tconv_kernel<<<dim3(32, 32), 256, 0, stream>>>(Wk, Wtk, 1024, 1024);
        tconv_kernel<<<dim3(32, 32), 256, 0, stream>>>(Wv, Wtv, 1024, 1024);
        tconv_kernel<<<dim3(32, 32), 256, 0, stream>>>(Wo, Wto, 1024, 1024);
        tconv_kernel<<<dim3(128, 32), 256, 0, stream>>>(W1, Wt1, 1024, 4096);
        tconv_kernel<<<dim3(32, 128), 256, 0, stream>>>(W2, Wt2, 4096, 1024);
    }

    semb_kernel<<<4, 256, 0, stream>>>(ts, semb);
    ada_part_kernel<<<dim3(16, 16), 256, 0, stream>>>(semb, Wada, adap);
    ada_red_kernel<<<32, 256, 0, stream>>>(adap, bada, ss);
    adaln_kernel<<<MROWS, 256, 0, stream>>>(src, ss, xb);

    if (BIG) {
        gemm_bt<0><<<dim3(8, 32, 3), 256, 0, stream>>>(xb, Wtq, Wtk, Wtv, bq, bk, bv, nullptr,
                                                       qb, kb, vb, nullptr, MROWS, DM, DM, DM);
        attn_mfma<<<dim3(SEQ / 64, NH, BATCH), 256, 0, stream>>>(qb, kb, vb, attb, mask, ctxb);
        gemm_bt<1><<<dim3(8, 32), 256, 0, stream>>>(ctxb, Wto, Wto, Wto, bo, bo, bo, xb,
                                                    x2, x2, x2, nullptr, MROWS, DM, DM, DM);
        ln2_kernel<<<MROWS, 256, 0, stream>>>(x2, g2, bt2, hb);
        for (int nc = 0; nc < 4; ++nc) {
            const unsigned short* w1c = Wt1 + (size_t)nc * 1024 * 1024;
            const float* b1c = b1 + nc * 1024;
            gemm_bt<2><<<dim3(8, 32), 256, 0, stream>>>(hb, w1c, w1c, w1c, b1c, b1c, b1c,
                                                        nullptr, mid, mid, mid, nullptr,
                                                        MROWS, DM, DM, DM);
            const unsigned short* w2c = Wt2 + nc * 1024;
            if (nc == 0)
                gemm_bt<3><<<dim3(8, 32), 256, 0, stream>>>(mid, w2c, w2c, w2c, b2, b2, b2,
                                                            x2, nullptr, nullptr, nullptr, out,
                                                            MROWS, DM, DM, DFF);
            else
                gemm_bt<4><<<dim3(8, 32), 256, 0, stream>>>(mid, w2c, w2c, w2c,
                                                            nullptr, nullptr, nullptr, nullptr,
                                                            nullptr, nullptr, nullptr, out,
                                                            MROWS, DM, DM, DFF);
        }
    } else {
        mfma_gemm<0><<<dim3(8, 32, 3), 256, 0, stream>>>(xb, Wq, Wk, Wv, bq, bk, bv, nullptr,
                                                         qb, kb, vb, nullptr, MROWS, DM, DM, DM);
        attn_mfma<<<dim3(SEQ / 64, NH, BATCH), 256, 0, stream>>>(qb, kb, vb, attb, mask, ctxb);
        mfma_gemm<1><<<dim3(8, 32), 256, 0, stream>>>(ctxb, Wo, Wo, Wo, bo, bo, bo, xb,
                                                      x2, x2, x2, nullptr, MROWS, DM, DM, DM);
        ln2_kernel<<<MROWS, 256, 0, stream>>>(x2, g2, bt2, hb);
        for (int nc = 0; nc < 4; ++nc) {
            const float* w1c = W1 + nc * 1024;
            const float* b1c = b1 + nc * 1024;
            mfma_gemm<2><<<dim3(8, 32), 256, 0, stream>>>(hb, w1c, w1c, w1c, b1c, b1c, b1c,
                                                          nullptr, mid, mid, mid, nullptr,
                                                          MROWS, DM, DM, DFF);
            const float* w2c = W2 + (size_t)nc * 1024 * DM;
            if (nc == 0)
                mfma_gemm<3><<<dim3(8, 32), 256, 0, stream>>>(mid, w2c, w2c, w2c, b2, b2, b2,
                                                              x2, nullptr, nullptr, nullptr,
                                                              out, MROWS, DM, DM, DM);
            else
                mfma_gemm<4><<<dim3(8, 32), 256, 0, stream>>>(mid, w2c, w2c, w2c,
                                                              nullptr, nullptr, nullptr,
                                                              nullptr, nullptr, nullptr,
                                                              nullptr, out, MROWS, DM, DM, DM);
        }
    }
}